// Round 13
// baseline (194.518 us; speedup 1.0000x reference)
//
#include <hip/hip_runtime.h>
#include <hip/hip_bf16.h>

typedef unsigned short u16;
typedef unsigned int u32;
typedef __attribute__((ext_vector_type(4))) short short4v;  // mfma 16x16x16 A/B frag (2 VGPRs)
typedef __attribute__((ext_vector_type(4))) float f32x4;    // mfma C/D frag

#define NN 30
#define FF 4
#define EE 870
#define BSZ 32
#define CC 64
#define TT 128
#define NF 120
#define TSTRIDE 15240
#define OUTHALF 487680
#define AST 68            // S row stride (u16)
#define WST 68            // LDS weight row stride (u16)
#define NSETS 3           // channel-sets per block (4 waves each)
#define NUNITS 2048       // BSZ*CC total channel-chains
#define NBLK 683          // ceil(2048/3)

// ws global layout at +256 (u16, o-major: w[o*64+k] = W[k][o]):
//   +0 W2T | +4096 A1T | +8192 A2T | +12288 V1T | +16384 V2T
// at +256+45056: u32 gmask[BSZ*NN]
#define WS_WOFF 256
#define WS_MASKOFF (256 + 45056)

__device__ __forceinline__ float bf2f(u16 u) {
    union { u32 i; float f; } v; v.i = ((u32)u) << 16; return v.f;
}
__device__ __forceinline__ u16 f2bf(float f) {
    __hip_bfloat16 h = __float2bfloat16(f); return *(u16*)&h;
}
// fast RNE f32->bf16 (finite values): 4 VALU instead of libcall
__device__ __forceinline__ u16 f2bf_fast(float f) {
    union { float f; u32 u; } v; v.f = f;
    return (u16)((v.u + 0x7FFFu + ((v.u >> 16) & 1u)) >> 16);
}
__device__ __forceinline__ float ldv(const void* p, int idx, int isbf) {
    if (isbf) return bf2f(((const u16*)p)[idx]);
    return ((const float*)p)[idx];
}
__device__ __forceinline__ float softplus_clip(float z) {
    float sp = fmaxf(z, 0.f) + log1pf(expf(-fabsf(z)));
    return fminf(fmaxf(sp, 1e-8f), 100.f);
}
__device__ __forceinline__ f32x4 MFMA16(short4v a, short4v b, f32x4 c) {
    return __builtin_amdgcn_mfma_f32_16x16x16bf16_1k(a, b, c, 0, 0, 0);
}

__device__ __forceinline__ int probe_isbf(const u16* g, int lane) {
    int hit = (g[2 * lane] == 0x3F80u) | (g[128 + 2 * lane] == 0x3F80u);
    unsigned long long b = __ballot(hit);
    return (b != 0ull) ? 1 : 0;
}

// ---- prep: transpose the five 64x64 weights to o-major bf16; build edge masks ----
__global__ void prep_ws(const void* __restrict__ mW2,
                        const void* __restrict__ aW1, const void* __restrict__ aW2,
                        const void* __restrict__ vW1, const void* __restrict__ vW2,
                        const void* __restrict__ graph,
                        u16* __restrict__ wsW, u32* __restrict__ wsMask) {
    const int lane = threadIdx.x & 63;
    const int isbf = probe_isbf((const u16*)graph, lane);
    const int gtid = blockIdx.x * blockDim.x + threadIdx.x;
    const int gstr = gridDim.x * blockDim.x;
    for (int idx = gtid; idx < 4096; idx += gstr) {
        int k = idx >> 6, o = idx & 63;
        int d = o * 64 + k;
        wsW[d]         = f2bf(ldv(mW2, idx, isbf));
        wsW[4096 + d]  = f2bf(ldv(aW1, idx, isbf));
        wsW[8192 + d]  = f2bf(ldv(aW2, idx, isbf));
        wsW[12288 + d] = f2bf(ldv(vW1, idx, isbf));
        wsW[16384 + d] = f2bf(ldv(vW2, idx, isbf));
    }
    for (int idx = gtid; idx < BSZ * NN; idx += gstr) {
        int b = idx / NN, i = idx % NN;
        u32 m = 0;
        for (int e = 0; e < 29; e++)
            if (ldv(graph, b * EE + i * 29 + e, isbf) > 0.5f) m |= (1u << e);
        wsMask[idx] = m;
    }
}

__global__ __launch_bounds__(768, 6)
void sim_fused(const void* __restrict__ data,
               const void* __restrict__ graph,
               const void* __restrict__ mW1, const void* __restrict__ mB1,
               const void* __restrict__ mB2,
               const void* __restrict__ aB1, const void* __restrict__ aB2,
               const void* __restrict__ aB3,
               const void* __restrict__ vB1, const void* __restrict__ vB2,
               const void* __restrict__ vB3,
               const void* __restrict__ aW3, const void* __restrict__ vW3,
               const u16* __restrict__ wsW, const u32* __restrict__ wsMask,
               void* __restrict__ out)
{
    // three independent channel-sets share one weight copy (sets may span bs)
    __shared__ __align__(16) float xN[NSETS][NF];
    __shared__ __align__(16) u16 pJs[NSETS][NN * 64];
    __shared__ __align__(16) u32 gmaskS[NSETS][32];
    __shared__ __align__(16) u16 S[NSETS][32 * AST];
    __shared__ __align__(16) u16 lwM2[64 * WST];
    __shared__ __align__(16) u16 lwH1m[64 * WST];
    __shared__ __align__(16) u16 lwH2m[64 * WST];
    __shared__ __align__(16) u16 lwH1v[64 * WST];
    __shared__ __align__(16) u16 lwH2v[64 * WST];
    __shared__ __align__(16) float biasL[5 * 64];  // mB2|aB1|aB2|vB1|vB2

    const int tid  = threadIdx.x;
    const int lane = tid & 63;
    const int wv   = tid >> 6;        // 0..11
    const int set  = wv >> 2;         // 0..2 : channel-set
    const int swv  = wv & 3;          // 0..3 within set
    const int ln15 = lane & 15;
    const int quad = lane >> 4;
    const int isbf = probe_isbf((const u16*)graph, lane);

    const int unit  = blockIdx.x * NSETS + set;    // global channel-chain id
    const int valid = (unit < NUNITS);
    const int u     = valid ? unit : (NUNITS - 1);
    const int bs    = u >> 6;
    const int c     = u & 63;

    const bool isMean = (swv < 2);
    const int nb = swv & 1;           // this wave's 16-node block

    // ---- stage weights global ws -> LDS (restride 64 -> WST), 768 threads ----
    {
        const u32* w32 = (const u32*)wsW;
        for (int idx = tid; idx < 2048; idx += 768) {   // 64 rows x 32 u32
            int o = idx >> 5, kw = idx & 31;
            int d = o * (WST / 2) + kw;
            ((u32*)lwM2)[d]  = w32[idx];
            ((u32*)lwH1m)[d] = w32[2048 + idx];
            ((u32*)lwH2m)[d] = w32[4096 + idx];
            ((u32*)lwH1v)[d] = w32[6144 + idx];
            ((u32*)lwH2v)[d] = w32[8192 + idx];
        }
    }
    if (tid < 64) {
        biasL[tid]       = ldv(mB2, tid, isbf);
        biasL[64 + tid]  = ldv(aB1, tid, isbf);
        biasL[128 + tid] = ldv(aB2, tid, isbf);
        biasL[192 + tid] = ldv(vB1, tid, isbf);
        biasL[256 + tid] = ldv(vB2, tid, isbf);
    }
    if (tid < NSETS * 32) {           // per-set edge masks
        int ss = tid >> 5, node = tid & 31;
        int us = blockIdx.x * NSETS + ss;
        int ub = (us < NUNITS ? us : NUNITS - 1) >> 6;
        gmaskS[ss][node] = (node < NN) ? wsMask[ub * NN + node] : 0u;
    }
    if (tid < NSETS * 128) {          // zero pad rows 30,31 of all sets' S
        int s2 = tid >> 7, row = 30 + ((tid >> 6) & 1);
        S[s2][row * AST + (tid & 63)] = 0;
    }

    float w1r[8];
#pragma unroll
    for (int k = 0; k < 8; k++) w1r[k] = ldv(mW1, k * 64 + lane, isbf);
    const float b1r = ldv(mB1, lane, isbf);
    float b3r[4];
#pragma unroll
    for (int r = 0; r < 4; r++) b3r[r] = ldv(isMean ? aB3 : vB3, r, isbf);

    const u16* wH1 = isMean ? lwH1m : lwH1v;
    const u16* wH2 = isMean ? lwH2m : lwH2v;
    const float* bAgg = biasL;
    const float* bH1  = isMean ? (biasL + 64)  : (biasL + 192);
    const float* bH2  = isMean ? (biasL + 128) : (biasL + 256);

    // ---- W3^T A-fragments in registers (16x64 padded; rows>=4 zero) ----
    const void* W3src = isMean ? aW3 : vW3;
    short4v eA[4];
#pragma unroll
    for (int kb = 0; kb < 4; kb++) {
        union { short4v v; u16 s[4]; } pk;
#pragma unroll
        for (int j = 0; j < 4; j++) {
            int k = kb * 16 + quad * 4 + j;
            pk.s[j] = (ln15 < 4)
                ? (isbf ? ((const u16*)W3src)[k * 4 + ln15]
                        : f2bf(((const float*)W3src)[k * 4 + ln15]))
                : (u16)0;
        }
        eA[kb] = pk.v;
    }

    // ---- stage this set's channel features (set groups align to 256 threads) ----
    const int setTid = tid & 255;
    if (isbf) {
        if (setTid < 60) {
            u32 w = ((const u32*)data)[((bs * TT + 2 * c) * NF) / 2 + setTid];
            xN[set][setTid * 2]     = bf2f((u16)(w & 0xFFFF));
            xN[set][setTid * 2 + 1] = bf2f((u16)(w >> 16));
        }
    } else {
        if (setTid < NF) xN[set][setTid] = ((const float*)data)[(bs * TT + 2 * c) * NF + setTid];
    }

    __syncthreads();

    const int myNode = nb * 16 + ln15;
    const float ngp = (myNode < NN) ? (float)__popc(gmaskS[set][myNode]) : 0.f;

    // transposed-chain layer: register B-frag in, register B-frag out
    auto runLayer = [&](const u16* wl, const float* bl, const short4v* Bin,
                        short4v* Bout, float bscale, bool doRelu) {
#pragma unroll
        for (int fb = 0; fb < 4; fb++) {
            f32x4 acc = {0.f, 0.f, 0.f, 0.f};
#pragma unroll
            for (int kb = 0; kb < 4; kb++) {
                short4v a = *(const short4v*)&wl[(fb * 16 + ln15) * WST + kb * 16 + quad * 4];
                acc = MFMA16(a, Bin[kb], acc);
            }
            float4 bv = *(const float4*)&bl[fb * 16 + quad * 4];
            union { short4v v; u16 s[4]; } pk;
#pragma unroll
            for (int r = 0; r < 4; r++) {
                float val = acc[r] + bscale * (&bv.x)[r];
                if (doRelu) val = fmaxf(val, 0.f);
                pk.s[r] = f2bf_fast(val);
            }
            Bout[fb] = pk.v;
        }
    };

    for (int step = 0; step < 2; step++) {
        // ---- pJ[j][h] = x_j . W1[4:8, h]  (bf16 in LDS) ----
        for (int i = swv; i < NN; i += 4) {
            float4 xv = *(const float4*)&xN[set][i * 4];
            pJs[set][i * 64 + lane] =
                f2bf_fast(xv.x * w1r[4] + xv.y * w1r[5] + xv.z * w1r[6] + xv.w * w1r[7]);
        }
        __syncthreads();

        // ---- edge accumulation: S[i][h] = sum_{j active} relu(pI + pJ) ----
        for (int i = swv; i < NN; i += 4) {
            float4 xv = *(const float4*)&xN[set][i * 4];
            float pI = b1r + xv.x * w1r[0] + xv.y * w1r[1] + xv.z * w1r[2] + xv.w * w1r[3];
            u32 gm = __builtin_amdgcn_readfirstlane(gmaskS[set][i]);
            float s = 0.f;
#pragma unroll
            for (int e = 0; e < 29; e++) {
                if (gm & (1u << e)) {
                    int j = e + (e >= i);
                    s += fmaxf(pI + bf2f(pJs[set][j * 64 + lane]), 0.f);
                }
            }
            S[set][i * AST + lane] = f2bf_fast(s);
        }
        __syncthreads();

        // ---- S^T B-fragments ----
        short4v Bs[4], Ba[4], Bb[4];
#pragma unroll
        for (int kb = 0; kb < 4; kb++)
            Bs[kb] = *(const short4v*)&S[set][(nb * 16 + ln15) * AST + kb * 16 + quad * 4];

        // ---- register-chained MLP: agg -> h1 -> h2 (no LDS round-trips) ----
        runLayer(lwM2, bAgg, Bs, Ba, ngp, false);   // agg = S@W2 + ng*b2
        runLayer(wH1,  bH1,  Ba, Bb, 1.f, true);    // h1 = relu(agg@W1+b1)
        runLayer(wH2,  bH2,  Bb, Ba, 1.f, true);    // h2 = relu(h1@W2+b2)

        // ---- out layer: D = W3T(reg) @ h2^T ----
        {
            f32x4 acc = {0.f, 0.f, 0.f, 0.f};
#pragma unroll
            for (int kb = 0; kb < 4; kb++) acc = MFMA16(eA[kb], Ba[kb], acc);
            const int n = nb * 16 + ln15;
            const int t = 2 * c + step;
            if (quad == 0 && n < NN) {
                float v[4];
#pragma unroll
                for (int r = 0; r < 4; r++) v[r] = acc[r] + b3r[r];
                if (!isMean) {
#pragma unroll
                    for (int r = 0; r < 4; r++) v[r] = softplus_clip(v[r]);
                }
                if (valid && t < 127) {
                    size_t o = (size_t)bs * TSTRIDE + (size_t)t * NF + n * 4
                             + (isMean ? 0 : OUTHALF);
                    if (isbf) {
                        u16* op = (u16*)out;
                        u32 lo = (u32)f2bf_fast(v[0]) | ((u32)f2bf_fast(v[1]) << 16);
                        u32 hi = (u32)f2bf_fast(v[2]) | ((u32)f2bf_fast(v[3]) << 16);
                        *(u32*)&op[o] = lo;
                        *(u32*)&op[o + 2] = hi;
                    } else {
                        float* op = (float*)out;
                        op[o] = v[0]; op[o+1] = v[1]; op[o+2] = v[2]; op[o+3] = v[3];
                    }
                }
                if (isMean && step == 0) {
                    xN[set][n*4]   = v[0]; xN[set][n*4+1] = v[1];
                    xN[set][n*4+2] = v[2]; xN[set][n*4+3] = v[3];
                }
            }
        }
        __syncthreads();   // xN/pJ/S step boundary
    }
}

extern "C" void kernel_launch(void* const* d_in, const int* in_sizes, int n_in,
                              void* d_out, int out_size, void* d_ws, size_t ws_size,
                              hipStream_t stream) {
    (void)in_sizes; (void)n_in; (void)out_size; (void)ws_size;

    const void* data  = d_in[0];
    const void* graph = d_in[1];
    const void* mW1 = d_in[2];  const void* mB1 = d_in[3];
    const void* mW2 = d_in[4];  const void* mB2 = d_in[5];
    const void* aW1 = d_in[6];  const void* aB1 = d_in[7];
    const void* aW2 = d_in[8];  const void* aB2 = d_in[9];
    const void* aW3 = d_in[10]; const void* aB3 = d_in[11];
    const void* vW1 = d_in[12]; const void* vB1 = d_in[13];
    const void* vW2 = d_in[14]; const void* vB2 = d_in[15];
    const void* vW3 = d_in[16]; const void* vB3 = d_in[17];

    u16* wsW    = (u16*)((char*)d_ws + WS_WOFF);
    u32* wsMask = (u32*)((char*)d_ws + WS_MASKOFF);

    prep_ws<<<8, 256, 0, stream>>>(mW2, aW1, aW2, vW1, vW2,
                                   graph, wsW, wsMask);

    sim_fused<<<NBLK, 768, 0, stream>>>(data, graph,
        mW1, mB1, mB2, aB1, aB2, aB3, vB1, vB2, vB3,
        aW3, vW3, wsW, wsMask, d_out);
}

// Round 14
// 154.745 us; speedup vs baseline: 1.2570x; 1.2570x over previous
//
#include <hip/hip_runtime.h>
#include <hip/hip_bf16.h>

typedef unsigned short u16;
typedef unsigned int u32;
typedef __attribute__((ext_vector_type(4))) short short4v;  // mfma 16x16x16 A/B frag (2 VGPRs)
typedef __attribute__((ext_vector_type(4))) float f32x4;    // mfma C/D frag

#define NN 30
#define FF 4
#define EE 870
#define BSZ 32
#define CC 64
#define TT 128
#define NF 120
#define TSTRIDE 15240
#define OUTHALF 487680
#define AST 68            // S row stride (u16)
#define WST 68            // LDS weight row stride (u16)
#define NCPB 2            // channels per SET
#define BPB  16           // blocks per bs

// ws global layout at +256 (u16, o-major: w[o*64+k] = W[k][o]):
//   +0 W2T | +4096 A1T | +8192 A2T | +12288 V1T | +16384 V2T
// at +256+45056: u32 gmask[BSZ*NN]
#define WS_WOFF 256
#define WS_MASKOFF (256 + 45056)

__device__ __forceinline__ float bf2f(u16 u) {
    union { u32 i; float f; } v; v.i = ((u32)u) << 16; return v.f;
}
__device__ __forceinline__ u16 f2bf(float f) {
    __hip_bfloat16 h = __float2bfloat16(f); return *(u16*)&h;
}
// fast RNE f32->bf16 (finite values): ~4 VALU instead of libcall sequence
__device__ __forceinline__ u16 f2bf_fast(float f) {
    union { float f; u32 u; } v; v.f = f;
    return (u16)((v.u + 0x7FFFu + ((v.u >> 16) & 1u)) >> 16);
}
__device__ __forceinline__ float ldv(const void* p, int idx, int isbf) {
    if (isbf) return bf2f(((const u16*)p)[idx]);
    return ((const float*)p)[idx];
}
__device__ __forceinline__ float softplus_clip(float z) {
    float sp = fmaxf(z, 0.f) + log1pf(expf(-fabsf(z)));
    return fminf(fmaxf(sp, 1e-8f), 100.f);
}
__device__ __forceinline__ f32x4 MFMA16(short4v a, short4v b, f32x4 c) {
    return __builtin_amdgcn_mfma_f32_16x16x16bf16_1k(a, b, c, 0, 0, 0);
}

__device__ __forceinline__ int probe_isbf(const u16* g, int lane) {
    int hit = (g[2 * lane] == 0x3F80u) | (g[128 + 2 * lane] == 0x3F80u);
    unsigned long long b = __ballot(hit);
    return (b != 0ull) ? 1 : 0;
}

// ---- prep: transpose the five 64x64 weights to o-major bf16; build edge masks ----
__global__ void prep_ws(const void* __restrict__ mW2,
                        const void* __restrict__ aW1, const void* __restrict__ aW2,
                        const void* __restrict__ vW1, const void* __restrict__ vW2,
                        const void* __restrict__ graph,
                        u16* __restrict__ wsW, u32* __restrict__ wsMask) {
    const int lane = threadIdx.x & 63;
    const int isbf = probe_isbf((const u16*)graph, lane);
    const int gtid = blockIdx.x * blockDim.x + threadIdx.x;
    const int gstr = gridDim.x * blockDim.x;
    for (int idx = gtid; idx < 4096; idx += gstr) {
        int k = idx >> 6, o = idx & 63;
        int d = o * 64 + k;
        wsW[d]         = f2bf(ldv(mW2, idx, isbf));
        wsW[4096 + d]  = f2bf(ldv(aW1, idx, isbf));
        wsW[8192 + d]  = f2bf(ldv(aW2, idx, isbf));
        wsW[12288 + d] = f2bf(ldv(vW1, idx, isbf));
        wsW[16384 + d] = f2bf(ldv(vW2, idx, isbf));
    }
    for (int idx = gtid; idx < BSZ * NN; idx += gstr) {
        int b = idx / NN, i = idx % NN;
        u32 m = 0;
        for (int e = 0; e < 29; e++)
            if (ldv(graph, b * EE + i * 29 + e, isbf) > 0.5f) m |= (1u << e);
        wsMask[idx] = m;
    }
}

__global__ __launch_bounds__(512, 4)
void sim_fused(const void* __restrict__ data,
               const void* __restrict__ graph,
               const void* __restrict__ mW1, const void* __restrict__ mB1,
               const void* __restrict__ mB2,
               const void* __restrict__ aB1, const void* __restrict__ aB2,
               const void* __restrict__ aB3,
               const void* __restrict__ vB1, const void* __restrict__ vB2,
               const void* __restrict__ vB3,
               const void* __restrict__ aW3, const void* __restrict__ vW3,
               const u16* __restrict__ wsW, const u32* __restrict__ wsMask,
               void* __restrict__ out)
{
    // two independent channel-sets share one weight copy
    __shared__ __align__(16) float xN[2][NF];
    __shared__ __align__(16) u16 pJs[2][NN * 64];
    __shared__ __align__(16) u32 gmaskS[32];
    __shared__ __align__(16) u16 S[2][32 * AST];
    __shared__ __align__(16) u16 lwM2[64 * WST];
    __shared__ __align__(16) u16 lwH1m[64 * WST];
    __shared__ __align__(16) u16 lwH2m[64 * WST];
    __shared__ __align__(16) u16 lwH1v[64 * WST];
    __shared__ __align__(16) u16 lwH2v[64 * WST];
    __shared__ __align__(16) float biasL[5 * 64];  // mB2|aB1|aB2|vB1|vB2

    const int tid  = threadIdx.x;
    const int lane = tid & 63;
    const int wv   = tid >> 6;        // 0..7
    const int set  = wv >> 2;         // 0..1 : channel-set
    const int swv  = wv & 3;          // 0..3 within set
    const int ln15 = lane & 15;
    const int quad = lane >> 4;
    const int bs   = blockIdx.x / BPB;
    const int bg   = blockIdx.x % BPB;
    const int cg   = bg * 2 + set;    // channel group 0..31 (NCPB channels each)
    const int isbf = probe_isbf((const u16*)graph, lane);

    const bool isMean = (swv < 2);
    const int nb = swv & 1;           // this wave's 16-node block

    // ---- stage weights global ws -> LDS (restride 64 -> WST), 512 threads ----
    {
        const u32* w32 = (const u32*)wsW;
        for (int idx = tid; idx < 2048; idx += 512) {   // 64 rows x 32 u32
            int o = idx >> 5, kw = idx & 31;
            int d = o * (WST / 2) + kw;
            ((u32*)lwM2)[d]  = w32[idx];
            ((u32*)lwH1m)[d] = w32[2048 + idx];
            ((u32*)lwH2m)[d] = w32[4096 + idx];
            ((u32*)lwH1v)[d] = w32[6144 + idx];
            ((u32*)lwH2v)[d] = w32[8192 + idx];
        }
    }
    if (tid < 64) {
        biasL[tid]       = ldv(mB2, tid, isbf);
        biasL[64 + tid]  = ldv(aB1, tid, isbf);
        biasL[128 + tid] = ldv(aB2, tid, isbf);
        biasL[192 + tid] = ldv(vB1, tid, isbf);
        biasL[256 + tid] = ldv(vB2, tid, isbf);
    }
    if (tid < 32) gmaskS[tid] = (tid < NN) ? wsMask[bs * NN + tid] : 0u;
    if (tid < 256) {  // zero pad rows 30,31 of both sets' S (stay zero forever)
        int s2 = tid >> 7, row = 30 + ((tid >> 6) & 1);
        S[s2][row * AST + (tid & 63)] = 0;
    }

    float w1r[8];
#pragma unroll
    for (int k = 0; k < 8; k++) w1r[k] = ldv(mW1, k * 64 + lane, isbf);
    const float b1r = ldv(mB1, lane, isbf);
    float b3r[4];
#pragma unroll
    for (int r = 0; r < 4; r++) b3r[r] = ldv(isMean ? aB3 : vB3, r, isbf);

    const u16* wH1 = isMean ? lwH1m : lwH1v;
    const u16* wH2 = isMean ? lwH2m : lwH2v;
    const float* bAgg = biasL;
    const float* bH1  = isMean ? (biasL + 64)  : (biasL + 192);
    const float* bH2  = isMean ? (biasL + 128) : (biasL + 256);

    // ---- W3^T A-fragments in registers (16x64 padded; rows>=4 zero) ----
    const void* W3src = isMean ? aW3 : vW3;
    short4v eA[4];
#pragma unroll
    for (int kb = 0; kb < 4; kb++) {
        union { short4v v; u16 s[4]; } pk;
#pragma unroll
        for (int j = 0; j < 4; j++) {
            int k = kb * 16 + quad * 4 + j;
            pk.s[j] = (ln15 < 4)
                ? (isbf ? ((const u16*)W3src)[k * 4 + ln15]
                        : f2bf(((const float*)W3src)[k * 4 + ln15]))
                : (u16)0;
        }
        eA[kb] = pk.v;
    }

    __syncthreads();

    const int myNode = nb * 16 + ln15;
    const float ngp = (myNode < NN) ? (float)__popc(gmaskS[myNode]) : 0.f;

    // transposed-chain layer: register B-frag in, register B-frag out
    auto runLayer = [&](const u16* wl, const float* bl, const short4v* Bin,
                        short4v* Bout, float bscale, bool doRelu) {
#pragma unroll
        for (int fb = 0; fb < 4; fb++) {
            f32x4 acc = {0.f, 0.f, 0.f, 0.f};
#pragma unroll
            for (int kb = 0; kb < 4; kb++) {
                short4v a = *(const short4v*)&wl[(fb * 16 + ln15) * WST + kb * 16 + quad * 4];
                acc = MFMA16(a, Bin[kb], acc);
            }
            float4 bv = *(const float4*)&bl[fb * 16 + quad * 4];
            union { short4v v; u16 s[4]; } pk;
#pragma unroll
            for (int r = 0; r < 4; r++) {
                float val = acc[r] + bscale * (&bv.x)[r];
                if (doRelu) val = fmaxf(val, 0.f);
                pk.s[r] = f2bf_fast(val);
            }
            Bout[fb] = pk.v;
        }
    };

    const int setTid = tid & 255;

    for (int ci = 0; ci < NCPB; ci++) {
        const int c = cg * NCPB + ci;

        // ---- stage this set's channel features ----
        if (isbf) {
            if (setTid < 60) {
                u32 w = ((const u32*)data)[((bs * TT + 2 * c) * NF) / 2 + setTid];
                xN[set][setTid * 2]     = bf2f((u16)(w & 0xFFFF));
                xN[set][setTid * 2 + 1] = bf2f((u16)(w >> 16));
            }
        } else {
            if (setTid < NF) xN[set][setTid] = ((const float*)data)[(bs * TT + 2 * c) * NF + setTid];
        }
        __syncthreads();

        for (int step = 0; step < 2; step++) {
            // ---- pJ[j][h] = x_j . W1[4:8, h]  (bf16 in LDS) ----
            for (int i = swv; i < NN; i += 4) {
                float4 xv = *(const float4*)&xN[set][i * 4];
                pJs[set][i * 64 + lane] =
                    f2bf_fast(xv.x * w1r[4] + xv.y * w1r[5] + xv.z * w1r[6] + xv.w * w1r[7]);
            }
            __syncthreads();

            // ---- edge accumulation: S[i][h] = sum_{j active} relu(pI + pJ) ----
            for (int i = swv; i < NN; i += 4) {
                float4 xv = *(const float4*)&xN[set][i * 4];
                float pI = b1r + xv.x * w1r[0] + xv.y * w1r[1] + xv.z * w1r[2] + xv.w * w1r[3];
                u32 gm = __builtin_amdgcn_readfirstlane(gmaskS[i]);
                float s = 0.f;
#pragma unroll
                for (int e = 0; e < 29; e++) {
                    if (gm & (1u << e)) {
                        int j = e + (e >= i);
                        s += fmaxf(pI + bf2f(pJs[set][j * 64 + lane]), 0.f);
                    }
                }
                S[set][i * AST + lane] = f2bf_fast(s);
            }
            __syncthreads();

            // ---- S^T B-fragments ----
            short4v Bs[4], Ba[4], Bb[4];
#pragma unroll
            for (int kb = 0; kb < 4; kb++)
                Bs[kb] = *(const short4v*)&S[set][(nb * 16 + ln15) * AST + kb * 16 + quad * 4];

            // ---- register-chained MLP: agg -> h1 -> h2 (no LDS round-trips) ----
            runLayer(lwM2, bAgg, Bs, Ba, ngp, false);   // agg = S@W2 + ng*b2
            runLayer(wH1,  bH1,  Ba, Bb, 1.f, true);    // h1 = relu(agg@W1+b1)
            runLayer(wH2,  bH2,  Bb, Ba, 1.f, true);    // h2 = relu(h1@W2+b2)

            // ---- out layer: D = W3T(reg) @ h2^T ----
            {
                f32x4 acc = {0.f, 0.f, 0.f, 0.f};
#pragma unroll
                for (int kb = 0; kb < 4; kb++) acc = MFMA16(eA[kb], Ba[kb], acc);
                const int n = nb * 16 + ln15;
                const int t = 2 * c + step;
                if (quad == 0 && n < NN) {
                    float v[4];
#pragma unroll
                    for (int r = 0; r < 4; r++) v[r] = acc[r] + b3r[r];
                    if (!isMean) {
#pragma unroll
                        for (int r = 0; r < 4; r++) v[r] = softplus_clip(v[r]);
                    }
                    if (t < 127) {
                        size_t o = (size_t)bs * TSTRIDE + (size_t)t * NF + n * 4
                                 + (isMean ? 0 : OUTHALF);
                        if (isbf) {
                            u16* op = (u16*)out;
                            u32 lo = (u32)f2bf_fast(v[0]) | ((u32)f2bf_fast(v[1]) << 16);
                            u32 hi = (u32)f2bf_fast(v[2]) | ((u32)f2bf_fast(v[3]) << 16);
                            *(u32*)&op[o] = lo;
                            *(u32*)&op[o + 2] = hi;
                        } else {
                            float* op = (float*)out;
                            op[o] = v[0]; op[o+1] = v[1]; op[o+2] = v[2]; op[o+3] = v[3];
                        }
                    }
                    if (isMean && step == 0) {
                        xN[set][n*4]   = v[0]; xN[set][n*4+1] = v[1];
                        xN[set][n*4+2] = v[2]; xN[set][n*4+3] = v[3];
                    }
                }
            }
            __syncthreads();   // xN/pJ/S step boundary
        }
    }
}

extern "C" void kernel_launch(void* const* d_in, const int* in_sizes, int n_in,
                              void* d_out, int out_size, void* d_ws, size_t ws_size,
                              hipStream_t stream) {
    (void)in_sizes; (void)n_in; (void)out_size; (void)ws_size;

    const void* data  = d_in[0];
    const void* graph = d_in[1];
    const void* mW1 = d_in[2];  const void* mB1 = d_in[3];
    const void* mW2 = d_in[4];  const void* mB2 = d_in[5];
    const void* aW1 = d_in[6];  const void* aB1 = d_in[7];
    const void* aW2 = d_in[8];  const void* aB2 = d_in[9];
    const void* aW3 = d_in[10]; const void* aB3 = d_in[11];
    const void* vW1 = d_in[12]; const void* vB1 = d_in[13];
    const void* vW2 = d_in[14]; const void* vB2 = d_in[15];
    const void* vW3 = d_in[16]; const void* vB3 = d_in[17];

    u16* wsW    = (u16*)((char*)d_ws + WS_WOFF);
    u32* wsMask = (u32*)((char*)d_ws + WS_MASKOFF);

    prep_ws<<<8, 256, 0, stream>>>(mW2, aW1, aW2, vW1, vW2,
                                   graph, wsW, wsMask);

    sim_fused<<<BSZ * BPB, 512, 0, stream>>>(data, graph,
        mW1, mB1, mB2, aB1, aB2, aB3, vB1, vB2, vB3,
        aW3, vW3, wsW, wsMask, d_out);
}